// Round 5
// baseline (437.140 us; speedup 1.0000x reference)
//
#include <hip/hip_runtime.h>

typedef unsigned short u16;
typedef unsigned int   u32;
typedef __attribute__((ext_vector_type(2)))  u16          u16x2;
typedef __attribute__((ext_vector_type(4)))  unsigned int u32x4;
typedef __attribute__((ext_vector_type(4)))  float        f32x4;
typedef __attribute__((ext_vector_type(4)))  u16          u16x4;
typedef __attribute__((ext_vector_type(8)))  u16          u16x8;
typedef __attribute__((ext_vector_type(8)))  __bf16       bf16x8;
typedef __attribute__((ext_vector_type(16))) float        f32x16;

#define NB 2
#define NH 8
#define NS 2048
#define ND 128

static __device__ __forceinline__ u16 f2b(float x) {
  return __builtin_bit_cast(u16, (__bf16)x);
}
static __device__ __forceinline__ u32 pk2(float a, float b) {
  u16x2 t; t[0] = f2b(a); t[1] = f2b(b);
  return __builtin_bit_cast(u32, t);
}

// ---------------- merged pre-pass: k f32->bf16 ; v f32 -> vt bf16 transposed ----------------
__global__ __launch_bounds__(256) void prepass(const float* __restrict__ k,
                                               const float* __restrict__ v,
                                               u16* __restrict__ kb, u16* __restrict__ vt) {
  const int bid = blockIdx.x;
  const int t = threadIdx.x;
  if (bid < 4096) {                                  // k: 4M elems as f32x4
    int i = bid * 256 + t;
    f32x4 x = ((const f32x4*)k)[i];
    u16x4 o;
    o[0] = f2b(x[0]); o[1] = f2b(x[1]); o[2] = f2b(x[2]); o[3] = f2b(x[3]);
    ((u16x4*)kb)[i] = o;
    return;
  }
  __shared__ u16 Lt[128][40];
  const int vb = bid - 4096;                         // 1024 blocks
  const int bh = vb >> 6;
  const int s0 = (vb & 63) * 32;
  const float* src = v + (size_t)(bh * NS + s0) * ND;
  const int srow = t >> 3;
#pragma unroll
  for (int it = 0; it < 4; ++it) {
    int c4 = (t & 7) + 8 * it;
    f32x4 x = *(const f32x4*)(src + srow * ND + c4 * 4);
#pragma unroll
    for (int jj = 0; jj < 4; ++jj) Lt[c4 * 4 + jj][srow] = f2b(x[jj]);
  }
  __syncthreads();
  const int d = t >> 1, sh = t & 1;
  u32x4 a  = *(const u32x4*)&Lt[d][sh * 16];
  u32x4 bq = *(const u32x4*)&Lt[d][sh * 16 + 8];
  u16* dst = vt + (size_t)(bh * ND + d) * NS + s0 + sh * 16;
  *(u32x4*)dst       = a;
  *(u32x4*)(dst + 8) = bq;
}

// ---------------- async global->LDS 16B ----------------
static __device__ __forceinline__ void gll16(u16* l, const u16* g) {
  __builtin_amdgcn_global_load_lds((const __attribute__((address_space(1))) void*)g,
                                   (__attribute__((address_space(3))) void*)l, 16, 0, 0);
}

// ---------------- main fused kernel ----------------
// grid 512: h = bid&7 (XCD), qt = bid>>3 (32 q-rows per block)
// 8 waves: b = w&1, jp = (w>>1)&1 (kv parity), dh = w>>2 (d-half of output)
// K tiles shared per (b,jp) slot, double-buffered, ONE __syncthreads per step.
__global__ __launch_bounds__(512, 4) void retention_main(
    const float* __restrict__ qf32, const u16* __restrict__ kb, const u16* __restrict__ vt,
    const float* __restrict__ omask, float* __restrict__ out) {
  __shared__ u16 Kls[2][4][32][128];   // 64 KB: [dbuf][slot(b,jp)][kv row][d], source-XOR swizzled

  const int tid  = threadIdx.x;
  const int w    = tid >> 6;
  const int lane = tid & 63;
  const int l31  = lane & 31;
  const int hh   = lane >> 5;
  const int xl   = l31 & 15;

  const int h  = blockIdx.x & 7;
  const int qt = blockIdx.x >> 3;      // 0..63
  const int q0 = qt * 32;

  const int b    = w & 1;
  const int jp   = (w >> 1) & 1;
  const int dh   = w >> 2;
  const int slot = w & 3;
  const int bh   = b * NH + h;

  // ---- Q fragments (B-operand): col = q-row = l31, k = 8hh+0..7, d = 16ka+k
  bf16x8 qf[8];
  {
    const float* qrow = qf32 + ((size_t)(bh * NS) + q0 + l31) * ND + hh * 8;
#pragma unroll
    for (int ka = 0; ka < 8; ++ka) {
      f32x4 x0 = *(const f32x4*)(qrow + ka * 16);
      f32x4 x1 = *(const f32x4*)(qrow + ka * 16 + 4);
      u16x8 o;
      o[0] = f2b(x0[0]); o[1] = f2b(x0[1]); o[2] = f2b(x0[2]); o[3] = f2b(x0[3]);
      o[4] = f2b(x1[0]); o[5] = f2b(x1[1]); o[6] = f2b(x1[2]); o[7] = f2b(x1[3]);
      qf[ka] = __builtin_bit_cast(bf16x8, o);
    }
  }

  f32x16 acc[2];
#pragma unroll
  for (int n = 0; n < 2; ++n)
#pragma unroll
    for (int i = 0; i < 16; ++i) acc[n][i] = 0.0f;

  const u16* kstage = kb + (size_t)(bh * NS) * ND + jp * 32 * ND;   // tile T=jp, stride 2 tiles
  const float* mptr = omask + (size_t)h * NS * NS + (size_t)(q0 + l31) * NS + jp * 32 + 4 * hh;
  const u16* vptr = vt + ((size_t)(bh * ND) + dh * 64 + l31) * NS + jp * 32 + 8 * hh;

  // wave w stages rows [dh*16, dh*16+16) of its own slot's next tile
  auto STAGE = [&](int dbw) {
#pragma unroll
    for (int i = 0; i < 4; ++i) {
      int r0  = dh * 16 + i * 4;
      int row = r0 + (lane >> 4);
      int cc  = (lane & 15) ^ (row & 15);
      gll16(&Kls[dbw][slot][r0][0], kstage + row * 128 + cc * 8);
    }
    kstage += 2 * 32 * ND;
  };

  f32x4 m[4];
#pragma unroll
  for (int g = 0; g < 4; ++g) m[g] = *(const f32x4*)(mptr + 8 * g);
  mptr += 64;
  STAGE(0);
  __syncthreads();

#pragma unroll 1
  for (int t = 0; t < 32; ++t) {
    const int db = t & 1;
    if (t < 31) STAGE(db ^ 1);                 // gll16 into other buffer, in flight all step
    // V fragments for current tile (L2-resident) — issue early, consumed after QK^T
    u32x4 v00 = *(const u32x4*)(vptr);
    u32x4 v01 = *(const u32x4*)(vptr + 16);
    u32x4 v10 = *(const u32x4*)(vptr + 32 * (size_t)NS);
    u32x4 v11 = *(const u32x4*)(vptr + 32 * (size_t)NS + 16);
    vptr += 64;
    // QK^T (swapped): A = K (row=l31=kv), B = Q (col=l31=q) -> S^T
    const u16* Kt = &Kls[db][slot][0][0];
    f32x16 s;
#pragma unroll
    for (int i = 0; i < 16; ++i) s[i] = 0.0f;
    __builtin_amdgcn_s_setprio(1);
#pragma unroll
    for (int ka = 0; ka < 8; ++ka) {
      u32x4 raw = *(const u32x4*)(Kt + l31 * 128 + (((2 * ka + hh) ^ xl) * 8));
      s = __builtin_amdgcn_mfma_f32_32x32x16_bf16(__builtin_bit_cast(bf16x8, raw), qf[ka], s, 0, 0, 0);
    }
    __builtin_amdgcn_s_setprio(0);
    // P^T = S^T * mask, pack to PV A-frag via lane^32 exchange
    bf16x8 PA[2];
#pragma unroll
    for (int kk = 0; kk < 2; ++kk) {
      u32 A0 = pk2(s[8 * kk + 0] * m[2 * kk][0], s[8 * kk + 1] * m[2 * kk][1]);
      u32 A1 = pk2(s[8 * kk + 2] * m[2 * kk][2], s[8 * kk + 3] * m[2 * kk][3]);
      u32 B0 = pk2(s[8 * kk + 4] * m[2 * kk + 1][0], s[8 * kk + 5] * m[2 * kk + 1][1]);
      u32 B1 = pk2(s[8 * kk + 6] * m[2 * kk + 1][2], s[8 * kk + 7] * m[2 * kk + 1][3]);
      u32 sA0 = (u32)__shfl_xor((int)A0, 32);
      u32 sA1 = (u32)__shfl_xor((int)A1, 32);
      u32 sB0 = (u32)__shfl_xor((int)B0, 32);
      u32 sB1 = (u32)__shfl_xor((int)B1, 32);
      u32x4 W;
      W[0] = hh ? sB0 : A0;
      W[1] = hh ? sB1 : A1;
      W[2] = hh ? B0  : sA0;
      W[3] = hh ? B1  : sA1;
      PA[kk] = __builtin_bit_cast(bf16x8, W);
    }
    // mask prefetch for t+1 (m regs dead after pack; ~700cy ahead of use)
    if (t < 31) {
#pragma unroll
      for (int g = 0; g < 4; ++g) m[g] = *(const f32x4*)(mptr + 8 * g);
      mptr += 64;
    }
    // PV: A = P (row=l31=q), B = Vt (col=l31=d2)
    __builtin_amdgcn_s_setprio(1);
    acc[0] = __builtin_amdgcn_mfma_f32_32x32x16_bf16(PA[0], __builtin_bit_cast(bf16x8, v00), acc[0], 0, 0, 0);
    acc[0] = __builtin_amdgcn_mfma_f32_32x32x16_bf16(PA[1], __builtin_bit_cast(bf16x8, v01), acc[0], 0, 0, 0);
    acc[1] = __builtin_amdgcn_mfma_f32_32x32x16_bf16(PA[0], __builtin_bit_cast(bf16x8, v10), acc[1], 0, 0, 0);
    acc[1] = __builtin_amdgcn_mfma_f32_32x32x16_bf16(PA[1], __builtin_bit_cast(bf16x8, v11), acc[1], 0, 0, 0);
    __builtin_amdgcn_s_setprio(0);
    __syncthreads();
  }

  // ---- epilogue: jp-combine + cross-dh RMSNorm ----
  float* red = (float*)&Kls[0][0][0][0];   // [b*2+dh][32][64] f32 = 32 KB
  float* sb  = red + 8192;                 // [b*2+dh][32] row sums
  if (jp == 1) {
#pragma unroll
    for (int n = 0; n < 2; ++n)
#pragma unroll
      for (int r = 0; r < 16; ++r) {
        int qrow = (r & 3) + 8 * (r >> 2) + 4 * hh;
        red[(size_t)((b * 2 + dh) * 32 + qrow) * 64 + n * 32 + l31] = acc[n][r];
      }
  }
  __syncthreads();
  float ss[16];
  if (jp == 0) {
#pragma unroll
    for (int n = 0; n < 2; ++n)
#pragma unroll
      for (int r = 0; r < 16; ++r) {
        int qrow = (r & 3) + 8 * (r >> 2) + 4 * hh;
        acc[n][r] += red[(size_t)((b * 2 + dh) * 32 + qrow) * 64 + n * 32 + l31];
      }
#pragma unroll
    for (int r = 0; r < 16; ++r) ss[r] = acc[0][r] * acc[0][r] + acc[1][r] * acc[1][r];
#pragma unroll
    for (int msk = 1; msk <= 16; msk <<= 1)
#pragma unroll
      for (int r = 0; r < 16; ++r) ss[r] += __shfl_xor(ss[r], msk);
    if (l31 == 0) {
#pragma unroll
      for (int r = 0; r < 16; ++r) {
        int qrow = (r & 3) + 8 * (r >> 2) + 4 * hh;
        sb[(b * 2 + dh) * 32 + qrow] = ss[r];
      }
    }
  }
  __syncthreads();
  if (jp == 0) {
    float* orow = out + ((size_t)(bh * NS) + q0) * ND + dh * 64;
#pragma unroll
    for (int r = 0; r < 16; ++r) {
      int qrow = (r & 3) + 8 * (r >> 2) + 4 * hh;
      float tot = ss[r] + sb[(b * 2 + (dh ^ 1)) * 32 + qrow];
      float sc  = rsqrtf(tot * (1.0f / 128.0f) + 1e-6f);
#pragma unroll
      for (int n = 0; n < 2; ++n)
        orow[(size_t)qrow * ND + n * 32 + l31] = acc[n][r] * sc;
    }
  }
}

extern "C" void kernel_launch(void* const* d_in, const int* in_sizes, int n_in,
                              void* d_out, int out_size, void* d_ws, size_t ws_size,
                              hipStream_t stream) {
  const float* q  = (const float*)d_in[0];
  const float* k  = (const float*)d_in[1];
  const float* v  = (const float*)d_in[2];
  const float* om = (const float*)d_in[3];
  float* out = (float*)d_out;

  const int NELT = NB * NH * NS * ND;       // 4,194,304
  u16* kbuf = (u16*)d_ws;
  u16* vtb  = kbuf + NELT;

  prepass<<<4096 + 1024, 256, 0, stream>>>(k, v, kbuf, vtb);
  retention_main<<<512, 512, 0, stream>>>(q, kbuf, vtb, om, out);
}